// Round 16
// baseline (156.879 us; speedup 1.0000x reference)
//
#include <hip/hip_runtime.h>

#define NEXP 8
#define E_TOT 100000
#define EPB 64                  // edges per block (4 waves x 16)
#define NTILE 1563              // ceil(E/EPB)
#define HSTR 136                // hs row stride (elems): +8 pad, affine addrs

typedef __bf16 bf16x8 __attribute__((ext_vector_type(8)));
typedef float f32x4 __attribute__((ext_vector_type(4)));
typedef unsigned short u16x8 __attribute__((ext_vector_type(8)));

union BF8 { u16x8 u; bf16x8 b; };
union BW  { __bf16 h; unsigned short u; };

__device__ __forceinline__ unsigned short f2bf(float f) {
  unsigned int u = __float_as_uint(f);
  u += 0x7fffu + ((u >> 16) & 1u);           // RNE
  return (unsigned short)(u >> 16);
}

__device__ __forceinline__ bf16x8 fragld(const unsigned short* a, int off) {
  BF8 t;
  t.u = *(const u16x8*)(a + off);
  return t.b;
}

__device__ __forceinline__ bf16x8 frag_f32(const float* s) {
  float4 u0 = *(const float4*)s;
  float4 u1 = *(const float4*)(s + 4);
  BF8 t;
  t.u[0]=f2bf(u0.x); t.u[1]=f2bf(u0.y); t.u[2]=f2bf(u0.z); t.u[3]=f2bf(u0.w);
  t.u[4]=f2bf(u1.x); t.u[5]=f2bf(u1.y); t.u[6]=f2bf(u1.z); t.u[7]=f2bf(u1.w);
  return t.b;
}

// ---- pre-kernel: weights fp32 -> bf16 in FRAGMENT-CONTIGUOUS layout ----
// Per expert n (32768 u16): L1 [0,8192) 16 frags, L2 [8192,24576) 32 frags,
// L3 [24576,32768) 16 frags. Each frag = 512 u16 = 64 lanes x 8 elems.
// L1/L2 frag (t,s), lane (l15,gq), elem j = W[16t+l15][32s+8gq+j] (B-operand).
// L3 is OUTPUT-ROW PERMUTED: frag (t,s) row slot l15 holds W3 row (4*l15 + t).
__global__ void k_conv_w(const float* __restrict__ W1c, const float* __restrict__ W2p,
                         const float* __restrict__ W3p, unsigned short* __restrict__ wsW) {
  int gid = blockIdx.x * 256 + threadIdx.x;     // [0, 262144)
  int n = gid >> 15, p = gid & 32767;
  int idx, frag, t, s, row;
  const float* base;
  int K;
  if (p < 8192)       { idx = p;         frag = idx >> 9; t = frag >> 1; s = frag & 1;
                        base = W1c + (size_t)n * 8192;  K = 64; }
  else if (p < 24576) { idx = p - 8192;  frag = idx >> 9; t = frag >> 2; s = frag & 3;
                        base = W2p + (size_t)n * 16384; K = 128; }
  else                { idx = p - 24576; frag = idx >> 9; t = frag >> 2; s = frag & 3;
                        base = W3p + (size_t)n * 8192;  K = 128; }
  int r = idx & 511, lane = r >> 3, j = r & 7;
  int l15 = lane & 15, gq = lane >> 4;
  row = (p < 24576) ? (16 * t + l15) : (4 * l15 + t);   // L3 permuted
  wsW[gid] = f2bf(base[row * K + 32 * s + 8 * gq + j]);
}

// ---- pre-kernel: x fp32 -> bf16 ----
__global__ void k_conv_x(const float* __restrict__ xg, unsigned short* __restrict__ xb) {
  int gid = blockIdx.x * 256 + threadIdx.x;     // 800000 threads, 8 elems each
  const float* s = xg + (size_t)gid * 8;
  BF8 t;
  float4 a = *(const float4*)s, b = *(const float4*)(s + 4);
  t.u[0]=f2bf(a.x); t.u[1]=f2bf(a.y); t.u[2]=f2bf(a.z); t.u[3]=f2bf(a.w);
  t.u[4]=f2bf(b.x); t.u[5]=f2bf(b.y); t.u[6]=f2bf(b.z); t.u[7]=f2bf(b.w);
  *(u16x8*)(xb + (size_t)gid * 8) = t.u;
}

// ---- main kernel: R14 structure + params in LDS + fma-ized epilogue ----
// R15 rationale: R14 still issues ~2.4k VALU-class inst/thread for 40 MFMA.
// Cuts: (1) LN params move from 52 VGPRs (global loads + addressing) to LDS
// with affine ds_read immediates -- DS pipe, no VALU, frees ~52 regs (the
// thing pinning occupancy at 4 waves/SIMD); (2) epilogue (acc-mu)*rs ->
// fma(acc, rs, -mu*rs); (3) acc2 copy removed (array ref).
// Kept lessons: 16-edge waves (R13: 32-edge spills); affine padded hs; W3-
// permuted float4 stores; no wave_barrier/sched_barrier/mem-clobber asm;
// cap (256,3) untightened.
template <bool USEWS>
__global__ __launch_bounds__(256, 3) void k_main(
    const unsigned short* __restrict__ wsW, const unsigned short* __restrict__ xb,
    const float* __restrict__ xg,
    const float* __restrict__ W1c, const float* __restrict__ b1c,
    const float* __restrict__ g1p, const float* __restrict__ bt1p,
    const float* __restrict__ W2p, const float* __restrict__ b2p,
    const float* __restrict__ g2p, const float* __restrict__ bt2p,
    const float* __restrict__ W3p, const float* __restrict__ b3p,
    float* __restrict__ outp)
{
  __shared__ __attribute__((aligned(16))) unsigned short hs[EPB * HSTR]; // 17 KB activations
  __shared__ __attribute__((aligned(16))) float prm[832];                // LN params + b3

  // bijective XCD remap (12504 = 8 * 1563 exact)
  const int bid = blockIdx.x;
  const int g_  = (bid & 7) * NTILE + (bid >> 3);
  const int tile = g_ >> 3;
  const int n    = g_ & 7;
  const int e0   = tile * EPB;

  const int tid  = threadIdx.x;
  const int lane = tid & 63;
  const int wv   = tid >> 6;           // 0..3
  const int l15  = lane & 15;
  const int gq   = lane >> 4;          // 0..3
  const int wrow = wv * 16;            // wave's 16 edges within tile

  // ---- stage LN params into LDS (832 slots, strided; one barrier) ----
  for (int i = tid; i < 832; i += 256) {
    int grp = i >> 7, f = i & 127;
    float v;
    switch (grp) {
      case 0: v = b1c [n * 128 + f]; break;
      case 1: v = g1p [n * 128 + f]; break;
      case 2: v = bt1p[n * 128 + f]; break;
      case 3: v = b2p [n * 128 + f]; break;
      case 4: v = g2p [n * 128 + f]; break;
      case 5: v = bt2p[n * 128 + f]; break;
      default: v = b3p[n * 64 + f]; break;   // i in 768..831
    }
    prm[i] = v;
  }

  // ---- x A-fragment: lane holds x[edge = e0+wrow+l15][d = 32s+8gq+j] ----
  bf16x8 ax[2];
  {
    int e = e0 + wrow + l15;
    if (e >= E_TOT) e = E_TOT - 1;               // clamp; garbage never stored
    if (USEWS) {
#pragma unroll
      for (int s = 0; s < 2; ++s)
        ax[s] = fragld(xb, e * 64 + s * 32 + 8 * gq);
    } else {
#pragma unroll
      for (int s = 0; s < 2; ++s)
        ax[s] = frag_f32(xg + (size_t)e * 64 + s * 32 + 8 * gq);
    }
  }

  // weight fragment bases (fragment-contiguous bf16) or fp32 fallback
  const unsigned short* wf1 = wsW + (size_t)n * 32768;
  const unsigned short* wf2 = wf1 + 8192;
  const unsigned short* wf3 = wf1 + 24576;
  const float* W1n = W1c + (size_t)n * 8192;
  const float* W2n = W2p + (size_t)n * 16384;
  const float* W3n = W3p + (size_t)n * 8192;

  auto wfrag = [&](const unsigned short* wf, const float* Wn, int fidx, int row, int s, int K) {
    if (USEWS) return fragld(wf, (fidx << 9) + (lane << 3));
    return frag_f32(Wn + row * K + 32 * s + 8 * gq);
  };

  __syncthreads();   // prm ready

  // LN + SiLU + bf16 store of the wave's 16x128 slab into hs (padded layout).
  // A already contains bias. D layout: col = 16ct+l15, row = edge 4gq+j.
  // gamma/beta read from LDS (affine, DS pipe).
  auto ln_silu_store = [&](f32x4 (&A)[8], int pb) {
    f32x4 sm4 = A[0];
    f32x4 sq4 = A[0] * A[0];
#pragma unroll
    for (int ct = 1; ct < 8; ++ct) {
      f32x4 v = A[ct];
      sm4 += v;
      sq4 += v * v;
    }
#pragma unroll
    for (int m = 1; m <= 8; m <<= 1) {
      f32x4 so, qo;
#pragma unroll
      for (int j = 0; j < 4; ++j) {
        so[j] = __shfl_xor(sm4[j], m);
        qo[j] = __shfl_xor(sq4[j], m);
      }
      sm4 += so;
      sq4 += qo;
    }
    f32x4 mu  = sm4 * (1.f / 128.f);
    f32x4 var = sq4 * (1.f / 128.f) - mu * mu;
    f32x4 rs;
#pragma unroll
    for (int j = 0; j < 4; ++j) rs[j] = __builtin_amdgcn_rsqf(var[j] + 1e-5f);
    f32x4 murs = mu * rs;
    unsigned short* hbase = hs + (wrow + 4 * gq) * HSTR + l15;
    const float* gb = &prm[pb + 128 + l15];
    const float* bb = &prm[pb + 256 + l15];
#pragma unroll
    for (int ct = 0; ct < 8; ++ct) {
      float gv  = gb[ct * 16];            // ds_read, affine imm offsets
      float btv = bb[ct * 16];
      f32x4 t = A[ct] * rs - murs;        // packed fma
#pragma unroll
      for (int j = 0; j < 4; ++j) {
        float v = t[j] * gv + btv;
        v = v * __builtin_amdgcn_rcpf(1.f + __expf(-v));   // silu
        BW bw; bw.h = (__bf16)v;
        hbase[j * HSTR + ct * 16] = bw.u;
      }
    }
  };

  f32x4 acc[8];

  // ---- layer 1: [16 x 64] @ [64 x 128], C-in = b1 broadcast (from LDS) ----
  {
    const float* bbs = &prm[l15];
#pragma unroll
    for (int ct = 0; ct < 8; ++ct) {
      float bv = bbs[ct * 16];
      f32x4 b4 = {bv, bv, bv, bv};
      acc[ct] = b4;
    }
  }
#pragma unroll
  for (int s = 0; s < 2; ++s) {
#pragma unroll
    for (int ct = 0; ct < 8; ++ct) {
      bf16x8 b = wfrag(wf1, W1n, ct * 2 + s, 16 * ct + l15, s, 64);
      acc[ct] = __builtin_amdgcn_mfma_f32_16x16x32_bf16(ax[s], b, acc[ct], 0, 0, 0);
    }
  }
  ln_silu_store(acc, 0);

  // ---- layer 2: [16 x 128] @ [128 x 128], C-in = b2 broadcast (from LDS) ----
  const unsigned short* habase = hs + (wrow + l15) * HSTR + 8 * gq;
  {
    const float* bbs = &prm[384 + l15];
#pragma unroll
    for (int ct = 0; ct < 8; ++ct) {
      float bv = bbs[ct * 16];
      f32x4 b4 = {bv, bv, bv, bv};
      acc[ct] = b4;
    }
  }
#pragma unroll
  for (int ks = 0; ks < 4; ++ks) {
    bf16x8 a0 = fragld(habase, ks * 32);
#pragma unroll
    for (int ct = 0; ct < 8; ++ct) {
      bf16x8 b = wfrag(wf2, W2n, ct * 4 + ks, 16 * ct + l15, ks, 128);
      acc[ct] = __builtin_amdgcn_mfma_f32_16x16x32_bf16(a0, b, acc[ct], 0, 0, 0);
    }
  }
  ln_silu_store(acc, 384);

  // ---- layer 3: [16 x 128] @ [128 x 64] (row-permuted W3), store ----
  f32x4 a3[4];
  {
    float4 b34 = *(const float4*)&prm[768 + 4 * l15];  // one ds_read_b128
#pragma unroll
    for (int t = 0; t < 4; ++t) {
      float bv = ((const float*)&b34)[t];
      f32x4 b4 = {bv, bv, bv, bv};
      a3[t] = b4;
    }
  }
#pragma unroll
  for (int ks = 0; ks < 4; ++ks) {
    bf16x8 a0 = fragld(habase, ks * 32);
#pragma unroll
    for (int t = 0; t < 4; ++t) {
      bf16x8 b = wfrag(wf3, W3n, t * 4 + ks, 4 * l15 + t, ks, 128);
      a3[t] = __builtin_amdgcn_mfma_f32_16x16x32_bf16(a0, b, a3[t], 0, 0, 0);
    }
  }

  // out[n][e][d], fp32. Lane owns o = 4*l15..4*l15+3 (permuted W3) -> float4.
#pragma unroll
  for (int j = 0; j < 4; ++j) {
    int e = e0 + wrow + 4 * gq + j;
    if (e < E_TOT) {
      float4 o4;
      o4.x = a3[0][j]; o4.y = a3[1][j]; o4.z = a3[2][j]; o4.w = a3[3][j];
      *(float4*)(outp + ((size_t)n * E_TOT + e) * 64 + 4 * l15) = o4;
    }
  }
}

extern "C" void kernel_launch(void* const* d_in, const int* in_sizes, int n_in,
                              void* d_out, int out_size, void* d_ws, size_t ws_size,
                              hipStream_t stream) {
  (void)in_sizes; (void)n_in; (void)out_size;
  const float* xg   = (const float*)d_in[0];
  const float* W1c  = (const float*)d_in[1];
  const float* b1c  = (const float*)d_in[2];
  const float* g1p  = (const float*)d_in[3];
  const float* bt1p = (const float*)d_in[4];
  const float* W2p  = (const float*)d_in[5];
  const float* b2p  = (const float*)d_in[6];
  const float* g2p  = (const float*)d_in[7];
  const float* bt2p = (const float*)d_in[8];
  const float* W3p  = (const float*)d_in[9];
  const float* b3p  = (const float*)d_in[10];
  float* outp = (float*)d_out;

  const size_t WS_W = (size_t)NEXP * 32768 * sizeof(unsigned short);  // 512 KB
  const size_t WS_X = (size_t)E_TOT * 64 * sizeof(unsigned short);    // 12.8 MB
  const bool usews = ws_size >= WS_W + WS_X;

  dim3 grid(NEXP * NTILE, 1, 1);
  dim3 block(256, 1, 1);

  if (usews) {
    unsigned short* wsW = (unsigned short*)d_ws;
    unsigned short* xb  = wsW + (size_t)NEXP * 32768;
    k_conv_w<<<1024, 256, 0, stream>>>(W1c, W2p, W3p, wsW);
    k_conv_x<<<3125, 256, 0, stream>>>(xg, xb);
    k_main<true><<<grid, block, 0, stream>>>(wsW, xb, xg, W1c, b1c, g1p, bt1p,
                                             W2p, b2p, g2p, bt2p, W3p, b3p, outp);
  } else {
    k_main<false><<<grid, block, 0, stream>>>(nullptr, nullptr, xg, W1c, b1c, g1p, bt1p,
                                              W2p, b2p, g2p, bt2p, W3p, b3p, outp);
  }
}

// Round 17
// 141.244 us; speedup vs baseline: 1.1107x; 1.1107x over previous
//
#include <hip/hip_runtime.h>

#define NEXP 8
#define E_TOT 100000
#define EPB 128                 // edges per block (4 waves x 32)
#define NTILE 782               // ceil(E/EPB); 6256 blocks = 8*782 (bijective remap)
#define HSTR 136                // hs row stride (elems): pad, 16B-aligned b128 rows

typedef __bf16 bf16x8 __attribute__((ext_vector_type(8)));
typedef float f32x4 __attribute__((ext_vector_type(4)));
typedef unsigned short u16x8 __attribute__((ext_vector_type(8)));

union BF8 { u16x8 u; bf16x8 b; };
union BW  { __bf16 h; unsigned short u; };

__device__ __forceinline__ unsigned short f2bf(float f) {
  unsigned int u = __float_as_uint(f);
  u += 0x7fffu + ((u >> 16) & 1u);           // RNE
  return (unsigned short)(u >> 16);
}

__device__ __forceinline__ bf16x8 fragld(const unsigned short* a, int off) {
  BF8 t;
  t.u = *(const u16x8*)(a + off);
  return t.b;
}

__device__ __forceinline__ bf16x8 frag_f32(const float* s) {
  float4 u0 = *(const float4*)s;
  float4 u1 = *(const float4*)(s + 4);
  BF8 t;
  t.u[0]=f2bf(u0.x); t.u[1]=f2bf(u0.y); t.u[2]=f2bf(u0.z); t.u[3]=f2bf(u0.w);
  t.u[4]=f2bf(u1.x); t.u[5]=f2bf(u1.y); t.u[6]=f2bf(u1.z); t.u[7]=f2bf(u1.w);
  return t.b;
}

// ---- pre-kernel: weights fp32 -> bf16 in FRAGMENT-CONTIGUOUS layout ----
// Per expert n (32768 u16): L1 [0,8192) 16 frags, L2 [8192,24576) 32 frags,
// L3 [24576,32768) 16 frags. Frag = 512 u16 = 64 lanes x 8 elems.
// ROW PERMUTATIONS (so a lane's output features are contiguous):
//   L1/L2 frag (t,s) row slot l15 holds W row (8*l15 + t)  -> D feature 8*l15+t
//   L3     frag (t,s) row slot l15 holds W3 row (4*l15 + t) -> out 4*l15+t
// hs therefore stores features in NATURAL order (position 8*l15+ct = feature).
__global__ void k_conv_w(const float* __restrict__ W1c, const float* __restrict__ W2p,
                         const float* __restrict__ W3p, unsigned short* __restrict__ wsW) {
  int gid = blockIdx.x * 256 + threadIdx.x;     // [0, 262144)
  int n = gid >> 15, p = gid & 32767;
  int idx, frag, t, s, row;
  const float* base;
  int K;
  if (p < 8192)       { idx = p;         frag = idx >> 9; t = frag >> 1; s = frag & 1;
                        base = W1c + (size_t)n * 8192;  K = 64; }
  else if (p < 24576) { idx = p - 8192;  frag = idx >> 9; t = frag >> 2; s = frag & 3;
                        base = W2p + (size_t)n * 16384; K = 128; }
  else                { idx = p - 24576; frag = idx >> 9; t = frag >> 2; s = frag & 3;
                        base = W3p + (size_t)n * 8192;  K = 128; }
  int r = idx & 511, lane = r >> 3, j = r & 7;
  int l15 = lane & 15, gq = lane >> 4;
  row = (p < 24576) ? (8 * l15 + t) : (4 * l15 + t);   // contiguous-feature perm
  wsW[gid] = f2bf(base[row * K + 32 * s + 8 * gq + j]);
}

// ---- pre-kernel: x fp32 -> bf16 ----
__global__ void k_conv_x(const float* __restrict__ xg, unsigned short* __restrict__ xb) {
  int gid = blockIdx.x * 256 + threadIdx.x;     // 800000 threads, 8 elems each
  const float* s = xg + (size_t)gid * 8;
  BF8 t;
  float4 a = *(const float4*)s, b = *(const float4*)(s + 4);
  t.u[0]=f2bf(a.x); t.u[1]=f2bf(a.y); t.u[2]=f2bf(a.z); t.u[3]=f2bf(a.w);
  t.u[4]=f2bf(b.x); t.u[5]=f2bf(b.y); t.u[6]=f2bf(b.z); t.u[7]=f2bf(b.w);
  *(u16x8*)(xb + (size_t)gid * 8) = t.u;
}

// ---- main kernel: 32 edges/wave + contiguous-feature b128 epilogue ----
// R16 rationale: issue-slot-bound (VALU 59 + MFMA 14 + DS ~25 ~= saturation;
// occupancy 21->51% bought ~0). Cuts: (1) 32-edge waves halve per-wave fixed
// cost (feasible now params live in LDS -- R13's spill was the 52 param regs);
// (2) row-permuted W1/W2 make each lane's 8 features contiguous -> ONE
// ds_write_b128 per edge-row (was 8 scattered b16) and float4 gamma/beta/bias
// reads. hs keeps natural feature order (8*l15+ct IS the feature index).
// Pre-registered fallback: VGPR<60 or WRITE>>205MB => spill => revert to
// 16-edge keeping this epilogue.
template <bool USEWS>
__global__ __launch_bounds__(256, 3) void k_main(
    const unsigned short* __restrict__ wsW, const unsigned short* __restrict__ xb,
    const float* __restrict__ xg,
    const float* __restrict__ W1c, const float* __restrict__ b1c,
    const float* __restrict__ g1p, const float* __restrict__ bt1p,
    const float* __restrict__ W2p, const float* __restrict__ b2p,
    const float* __restrict__ g2p, const float* __restrict__ bt2p,
    const float* __restrict__ W3p, const float* __restrict__ b3p,
    float* __restrict__ outp)
{
  __shared__ __attribute__((aligned(16))) unsigned short hs[EPB * HSTR]; // 34 KB activations
  __shared__ __attribute__((aligned(16))) float prm[832];                // LN params + b3

  // bijective XCD remap (6256 = 8 * 782 exact)
  const int bid = blockIdx.x;
  const int g_  = (bid & 7) * NTILE + (bid >> 3);
  const int tile = g_ >> 3;
  const int n    = g_ & 7;
  const int e0   = tile * EPB;

  const int tid  = threadIdx.x;
  const int lane = tid & 63;
  const int wv   = tid >> 6;           // 0..3
  const int l15  = lane & 15;
  const int gq   = lane >> 4;          // 0..3
  const int wrow = wv * 32;            // wave's 32 edges within tile

  // ---- stage LN params into LDS (832 slots, strided; one barrier) ----
  for (int i = tid; i < 832; i += 256) {
    int grp = i >> 7, f = i & 127;
    float v;
    switch (grp) {
      case 0: v = b1c [n * 128 + f]; break;
      case 1: v = g1p [n * 128 + f]; break;
      case 2: v = bt1p[n * 128 + f]; break;
      case 3: v = b2p [n * 128 + f]; break;
      case 4: v = g2p [n * 128 + f]; break;
      case 5: v = bt2p[n * 128 + f]; break;
      default: v = b3p[n * 64 + f]; break;   // i in 768..831
    }
    prm[i] = v;
  }

  // ---- x A-fragments: lane holds x[edge = e0+wrow+16rt+l15][d = 32s+8gq+j] ----
  bf16x8 ax[2][2];
#pragma unroll
  for (int rt = 0; rt < 2; ++rt) {
    int e = e0 + wrow + 16 * rt + l15;
    if (e >= E_TOT) e = E_TOT - 1;               // clamp; garbage never stored
    if (USEWS) {
#pragma unroll
      for (int s = 0; s < 2; ++s)
        ax[rt][s] = fragld(xb, e * 64 + s * 32 + 8 * gq);
    } else {
#pragma unroll
      for (int s = 0; s < 2; ++s)
        ax[rt][s] = frag_f32(xg + (size_t)e * 64 + s * 32 + 8 * gq);
    }
  }

  // weight fragment bases (fragment-contiguous bf16) or fp32 fallback
  const unsigned short* wf1 = wsW + (size_t)n * 32768;
  const unsigned short* wf2 = wf1 + 8192;
  const unsigned short* wf3 = wf1 + 24576;
  const float* W1n = W1c + (size_t)n * 8192;
  const float* W2n = W2p + (size_t)n * 16384;
  const float* W3n = W3p + (size_t)n * 8192;

  auto wfrag = [&](const unsigned short* wf, const float* Wn, int fidx, int row, int s, int K) {
    if (USEWS) return fragld(wf, (fidx << 9) + (lane << 3));
    return frag_f32(Wn + row * K + 32 * s + 8 * gq);
  };

  __syncthreads();   // prm ready

  f32x4 acc[2][8];

  // LN + SiLU + bf16 store, contiguous-feature layout.
  // acc[rt][ct][j] = h[edge wrow+16rt+4gq+j][feature 8*l15+ct] (bias included).
  // Per edge-row (rt,j): pack 8 features -> one ds_write_b128 at hs[edge][8*l15].
  auto ln_silu_store = [&](int pb) {
#pragma unroll
    for (int rt = 0; rt < 2; ++rt) {
      f32x4 sm4 = acc[rt][0];
      f32x4 sq4 = acc[rt][0] * acc[rt][0];
#pragma unroll
      for (int ct = 1; ct < 8; ++ct) {
        f32x4 v = acc[rt][ct];
        sm4 += v;
        sq4 += v * v;
      }
#pragma unroll
      for (int m = 1; m <= 8; m <<= 1) {
        f32x4 so, qo;
#pragma unroll
        for (int j = 0; j < 4; ++j) {
          so[j] = __shfl_xor(sm4[j], m);
          qo[j] = __shfl_xor(sq4[j], m);
        }
        sm4 += so;
        sq4 += qo;
      }
      f32x4 mu  = sm4 * (1.f / 128.f);
      f32x4 var = sq4 * (1.f / 128.f) - mu * mu;
      f32x4 rs;
#pragma unroll
      for (int j = 0; j < 4; ++j) rs[j] = __builtin_amdgcn_rsqf(var[j] + 1e-5f);
      f32x4 murs = mu * rs;
      // gamma/beta for features 8*l15..8*l15+7: two float4 LDS reads each
      float4 g01 = *(const float4*)&prm[pb + 128 + 8 * l15];
      float4 g23 = *(const float4*)&prm[pb + 128 + 8 * l15 + 4];
      float4 t01 = *(const float4*)&prm[pb + 256 + 8 * l15];
      float4 t23 = *(const float4*)&prm[pb + 256 + 8 * l15 + 4];
      const float* gv  = (const float*)&g01;   // [0..3] then g23 [0..3]
      const float* gv2 = (const float*)&g23;
      const float* bv  = (const float*)&t01;
      const float* bv2 = (const float*)&t23;
      unsigned short* hbase = hs + (wrow + 16 * rt + 4 * gq) * HSTR + 8 * l15;
#pragma unroll
      for (int j = 0; j < 4; ++j) {
        BF8 t8;
#pragma unroll
        for (int ct = 0; ct < 8; ++ct) {
          float g = (ct < 4) ? gv[ct] : gv2[ct - 4];
          float bb = (ct < 4) ? bv[ct] : bv2[ct - 4];
          float v = acc[rt][ct][j] * rs[j] - murs[j];     // fma
          v = v * g + bb;                                 // fma
          v = v * __builtin_amdgcn_rcpf(1.f + __expf(-v)); // silu
          BW bw; bw.h = (__bf16)v;
          t8.u[ct] = bw.u;
        }
        *(u16x8*)(hbase + j * HSTR) = t8.u;   // one ds_write_b128 per edge-row
      }
    }
  };

  // ---- layer 1: [32 x 64] @ [64 x 128], C-in = b1 (features 8*l15+ct) ----
  {
    float4 b01 = *(const float4*)&prm[8 * l15];
    float4 b23 = *(const float4*)&prm[8 * l15 + 4];
    const float* bp  = (const float*)&b01;
    const float* bp2 = (const float*)&b23;
#pragma unroll
    for (int ct = 0; ct < 8; ++ct) {
      float bv = (ct < 4) ? bp[ct] : bp2[ct - 4];
      f32x4 b4 = {bv, bv, bv, bv};
      acc[0][ct] = b4;
      acc[1][ct] = b4;
    }
  }
#pragma unroll
  for (int s = 0; s < 2; ++s) {
#pragma unroll
    for (int ct = 0; ct < 8; ++ct) {
      bf16x8 b = wfrag(wf1, W1n, ct * 2 + s, 8 * l15 + ct, s, 64);
      acc[0][ct] = __builtin_amdgcn_mfma_f32_16x16x32_bf16(ax[0][s], b, acc[0][ct], 0, 0, 0);
      acc[1][ct] = __builtin_amdgcn_mfma_f32_16x16x32_bf16(ax[1][s], b, acc[1][ct], 0, 0, 0);
    }
  }
  ln_silu_store(0);

  // ---- layer 2: [32 x 128] @ [128 x 128], C-in = b2 ----
  const unsigned short* ha0 = hs + (wrow + l15) * HSTR + 8 * gq;
  const unsigned short* ha1 = hs + (wrow + 16 + l15) * HSTR + 8 * gq;
  {
    float4 b01 = *(const float4*)&prm[384 + 8 * l15];
    float4 b23 = *(const float4*)&prm[384 + 8 * l15 + 4];
    const float* bp  = (const float*)&b01;
    const float* bp2 = (const float*)&b23;
#pragma unroll
    for (int ct = 0; ct < 8; ++ct) {
      float bv = (ct < 4) ? bp[ct] : bp2[ct - 4];
      f32x4 b4 = {bv, bv, bv, bv};
      acc[0][ct] = b4;
      acc[1][ct] = b4;
    }
  }
#pragma unroll
  for (int ks = 0; ks < 4; ++ks) {
    bf16x8 a0 = fragld(ha0, ks * 32);
    bf16x8 a1 = fragld(ha1, ks * 32);
#pragma unroll
    for (int ct = 0; ct < 8; ++ct) {
      bf16x8 b = wfrag(wf2, W2n, ct * 4 + ks, 8 * l15 + ct, ks, 128);
      acc[0][ct] = __builtin_amdgcn_mfma_f32_16x16x32_bf16(a0, b, acc[0][ct], 0, 0, 0);
      acc[1][ct] = __builtin_amdgcn_mfma_f32_16x16x32_bf16(a1, b, acc[1][ct], 0, 0, 0);
    }
  }
  ln_silu_store(384);

  // ---- layer 3: [32 x 128] @ [128 x 64] (row-permuted W3), store ----
  f32x4 a3[2][4];
  {
    float4 b34 = *(const float4*)&prm[768 + 4 * l15];
#pragma unroll
    for (int t = 0; t < 4; ++t) {
      float bv = ((const float*)&b34)[t];
      f32x4 b4 = {bv, bv, bv, bv};
      a3[0][t] = b4;
      a3[1][t] = b4;
    }
  }
#pragma unroll
  for (int ks = 0; ks < 4; ++ks) {
    bf16x8 a0 = fragld(ha0, ks * 32);
    bf16x8 a1 = fragld(ha1, ks * 32);
#pragma unroll
    for (int t = 0; t < 4; ++t) {
      bf16x8 b = wfrag(wf3, W3n, t * 4 + ks, 4 * l15 + t, ks, 128);
      a3[0][t] = __builtin_amdgcn_mfma_f32_16x16x32_bf16(a0, b, a3[0][t], 0, 0, 0);
      a3[1][t] = __builtin_amdgcn_mfma_f32_16x16x32_bf16(a1, b, a3[1][t], 0, 0, 0);
    }
  }

  // out[n][e][d], fp32. Lane owns o = 4*l15..4*l15+3 -> float4 stores.
#pragma unroll
  for (int rt = 0; rt < 2; ++rt) {
#pragma unroll
    for (int j = 0; j < 4; ++j) {
      int e = e0 + wrow + 16 * rt + 4 * gq + j;
      if (e < E_TOT) {
        float4 o4;
        o4.x = a3[rt][0][j]; o4.y = a3[rt][1][j];
        o4.z = a3[rt][2][j]; o4.w = a3[rt][3][j];
        *(float4*)(outp + ((size_t)n * E_TOT + e) * 64 + 4 * l15) = o4;
      }
    }
  }
}

extern "C" void kernel_launch(void* const* d_in, const int* in_sizes, int n_in,
                              void* d_out, int out_size, void* d_ws, size_t ws_size,
                              hipStream_t stream) {
  (void)in_sizes; (void)n_in; (void)out_size;
  const float* xg   = (const float*)d_in[0];
  const float* W1c  = (const float*)d_in[1];
  const float* b1c  = (const float*)d_in[2];
  const float* g1p  = (const float*)d_in[3];
  const float* bt1p = (const float*)d_in[4];
  const float* W2p  = (const float*)d_in[5];
  const float* b2p  = (const float*)d_in[6];
  const float* g2p  = (const float*)d_in[7];
  const float* bt2p = (const float*)d_in[8];
  const float* W3p  = (const float*)d_in[9];
  const float* b3p  = (const float*)d_in[10];
  float* outp = (float*)d_out;

  const size_t WS_W = (size_t)NEXP * 32768 * sizeof(unsigned short);  // 512 KB
  const size_t WS_X = (size_t)E_TOT * 64 * sizeof(unsigned short);    // 12.8 MB
  const bool usews = ws_size >= WS_W + WS_X;

  dim3 grid(NEXP * NTILE, 1, 1);
  dim3 block(256, 1, 1);

  if (usews) {
    unsigned short* wsW = (unsigned short*)d_ws;
    unsigned short* xb  = wsW + (size_t)NEXP * 32768;
    k_conv_w<<<1024, 256, 0, stream>>>(W1c, W2p, W3p, wsW);
    k_conv_x<<<3125, 256, 0, stream>>>(xg, xb);
    k_main<true><<<grid, block, 0, stream>>>(wsW, xb, xg, W1c, b1c, g1p, bt1p,
                                             W2p, b2p, g2p, bt2p, W3p, b3p, outp);
  } else {
    k_main<false><<<grid, block, 0, stream>>>(nullptr, nullptr, xg, W1c, b1c, g1p, bt1p,
                                              W2p, b2p, g2p, bt2p, W3p, b3p, outp);
  }
}